// Round 1
// baseline (624.063 us; speedup 1.0000x reference)
//
#include <hip/hip_runtime.h>
#include <hip/hip_bf16.h>
#include <cstdint>
#include <cstddef>

#define BATCH 32
#define NPTS  2048

typedef __attribute__((ext_vector_type(8))) short bf16x8;   // 8 bf16 in 4 VGPRs (A/B frag)
typedef __attribute__((ext_vector_type(4))) float f32x4;    // C/D frag

__device__ inline unsigned short f2b(float v) {
    __hip_bfloat16 h = __float2bfloat16(v);
    return __builtin_bit_cast(unsigned short, h);
}

// ---------------- ws layout (bytes) ----------------
// dinv : float [B*N]            @ 0          (256 KB)
// mask : u32   [B*N*64]         @ 0x40000    (16 MB)   row i -> 64 words, bit t of word w = (dist(i, w*32+t) < 1)
// Y    : bf16  [B*N*256 max]    @ 17039360   (32 MB)   dinv-scaled GEMM B-operand, stride = current C
// H    : bf16  [B*N*128 max]    @ 50593792   (16 MB)   layer activations, stride = current C
// Wb   : bf16  [64*128+128*256] @ 67371008   (80 KB)
#define OFF_DINV 0
#define OFF_MASK 262144
#define OFF_Y    17039360
#define OFF_H    50593792
#define OFF_WB   67371008

// ---------------- kernel: convert W2/W3 to bf16 ----------------
__global__ __launch_bounds__(256) void k_cvtW(const float* __restrict__ W2,
                                              const float* __restrict__ W3,
                                              unsigned short* __restrict__ Wb) {
    int i = blockIdx.x * 256 + threadIdx.x;
    if (i < 64 * 128)  Wb[i] = f2b(W2[i]);
    if (i < 128 * 256) Wb[64 * 128 + i] = f2b(W3[i]);
}

// ---------------- kernel: mask bits + dinv ----------------
__global__ __launch_bounds__(256) void k_mask(const float* __restrict__ pts,
                                              float* __restrict__ dinv,
                                              uint32_t* __restrict__ mask) {
    const int b = blockIdx.y;
    const int i = blockIdx.x * 256 + threadIdx.x;
    __shared__ float px[NPTS], py[NPTS];
    const float2* P = (const float2*)(pts + (size_t)b * NPTS * 2);
    for (int j = threadIdx.x; j < NPTS; j += 256) { float2 p = P[j]; px[j] = p.x; py[j] = p.y; }
    __syncthreads();
    const float xi = px[i], yi = py[i];
    uint32_t* mrow = mask + ((size_t)b * NPTS + i) * 64;
    int cnt = 0;
    for (int w = 0; w < 64; ++w) {
        uint32_t bits = 0;
        const int j0 = w * 32;
        #pragma unroll
        for (int t = 0; t < 32; ++t) {
            float dx = xi - px[j0 + t], dy = yi - py[j0 + t];
            bits |= (dx * dx + dy * dy < 1.0f) ? (1u << t) : 0u;
        }
        cnt += __popc(bits);
        mrow[w] = bits;
    }
    // deg = popcount(row incl. self-bit) + 1 (PyG adds self-loop on top -> diag weight 2)
    dinv[b * NPTS + i] = 1.0f / sqrtf((float)(cnt + 1));
}

// ---------------- kernel: layer 1 via (An@p)@W1 (K=2 trick) ----------------
__global__ __launch_bounds__(256) void k_layer1(const float* __restrict__ pts,
                                                const float* __restrict__ W1,
                                                const float* __restrict__ b1,
                                                const float* __restrict__ dinv,
                                                const uint32_t* __restrict__ mask,
                                                unsigned short* __restrict__ H) {
    const int b = blockIdx.y;
    const int i = blockIdx.x * 256 + threadIdx.x;
    __shared__ float u[NPTS], v[NPTS];
    const float2* P = (const float2*)(pts + (size_t)b * NPTS * 2);
    const float* dv = dinv + b * NPTS;
    for (int j = threadIdx.x; j < NPTS; j += 256) {
        float d = dv[j]; float2 p = P[j];
        u[j] = d * p.x; v[j] = d * p.y;
    }
    __syncthreads();
    const uint32_t* mrow = mask + ((size_t)b * NPTS + i) * 64;
    float sx = 0.f, sy = 0.f;
    for (int w = 0; w < 64; ++w) {
        uint32_t bits = mrow[w];
        const int j0 = w * 32;
        #pragma unroll
        for (int t = 0; t < 32; ++t) {
            if (bits & (1u << t)) { sx += u[j0 + t]; sy += v[j0 + t]; }
        }
    }
    sx += u[i]; sy += v[i];   // diagonal weight 2 = self-bit (counted) + extra self-loop
    const float di = dv[i];
    unsigned short* h = H + ((size_t)b * NPTS + i) * 64;
    #pragma unroll
    for (int c = 0; c < 64; ++c) {
        float val = di * (sx * W1[c] + sy * W1[64 + c]) + b1[c];
        h[c] = f2b(fmaxf(val, 0.f));
    }
}

// ---------------- kernel: masked GCN GEMM  out = act(dinv_i*(A@Y) + bias) ----------------
// A[i][j] in {0,1,2} generated in-register from bitmask; Y bf16 [B][N][BN] (= dinv_j * G_j).
template<int BN, bool RELU, bool F32OUT>
__global__ __launch_bounds__(256) void k_gcn(const uint32_t* __restrict__ mask,
                                             const float* __restrict__ dinv,
                                             const unsigned short* __restrict__ Y,
                                             const float* __restrict__ bias,
                                             void* __restrict__ outp) {
    constexpr int BK = 64, BM = 128, LDT = BK + 8;
    const int b = blockIdx.y;
    const int row0 = blockIdx.x * BM;
    const int tid = threadIdx.x;
    const int lane = tid & 63, wv = tid >> 6;
    const int l15 = lane & 15, lg = lane >> 4;

    __shared__ alignas(16) unsigned short Yt[BN][LDT];  // transposed Y tile [col][k]
    __shared__ float sdinv[BM];
    if (tid < BM) sdinv[tid] = dinv[b * NPTS + row0 + tid];

    f32x4 acc[2][BN / 16];
    #pragma unroll
    for (int rf = 0; rf < 2; ++rf)
        #pragma unroll
        for (int nf = 0; nf < BN / 16; ++nf)
            acc[rf][nf] = (f32x4){0.f, 0.f, 0.f, 0.f};

    const int arow0 = row0 + wv * 32;
    const uint32_t* mrow0 = mask + ((size_t)b * NPTS + arow0 + l15) * 64;
    const uint32_t* mrow1 = mrow0 + 16 * 64;
    const int grow0 = arow0 + l15, grow1 = grow0 + 16;

    for (int kt = 0; kt < NPTS / BK; ++kt) {
        // ---- stage Y tile (transposed, +8 pad) ----
        const uint32_t* ysrc = (const uint32_t*)(Y + ((size_t)b * NPTS + kt * BK) * BN);
        #pragma unroll 4
        for (int idx = tid; idx < BK * BN / 2; idx += 256) {
            int j = idx / (BN / 2), cp = idx % (BN / 2);
            uint32_t val = ysrc[(size_t)j * (BN / 2) + cp];
            Yt[2 * cp][j]     = (unsigned short)(val & 0xffffu);
            Yt[2 * cp + 1][j] = (unsigned short)(val >> 16);
        }
        __syncthreads();

        #pragma unroll
        for (int kk = 0; kk < BK; kk += 32) {
            const int kbase = kk + lg * 8;
            const int jg0 = kt * BK + kbase;
            // ---- expand bitmask -> A fragments (diag folded in as 2.0) ----
            bf16x8 afr0, afr1;
            {
                uint32_t w0 = mrow0[kt * 2 + kk / 32];
                uint32_t w1 = mrow1[kt * 2 + kk / 32];
                uint32_t by0 = (w0 >> (lg * 8)) & 0xffu;
                uint32_t by1 = (w1 >> (lg * 8)) & 0xffu;
                #pragma unroll
                for (int e = 0; e < 8; ++e) {
                    int j = jg0 + e;
                    afr0[e] = (short)(((by0 >> e) & 1u) ? ((j == grow0) ? 0x4000 : 0x3F80) : 0);
                    afr1[e] = (short)(((by1 >> e) & 1u) ? ((j == grow1) ? 0x4000 : 0x3F80) : 0);
                }
            }
            #pragma unroll
            for (int nf = 0; nf < BN / 16; ++nf) {
                bf16x8 bfr = *(const bf16x8*)&Yt[nf * 16 + l15][kbase];
                acc[0][nf] = __builtin_amdgcn_mfma_f32_16x16x32_bf16(afr0, bfr, acc[0][nf], 0, 0, 0);
                acc[1][nf] = __builtin_amdgcn_mfma_f32_16x16x32_bf16(afr1, bfr, acc[1][nf], 0, 0, 0);
            }
        }
        __syncthreads();
    }

    // ---- epilogue ----
    #pragma unroll
    for (int rf = 0; rf < 2; ++rf) {
        #pragma unroll
        for (int nf = 0; nf < BN / 16; ++nf) {
            const int gc = nf * 16 + l15;
            const float bb = bias[gc];
            #pragma unroll
            for (int r = 0; r < 4; ++r) {
                const int lr = wv * 32 + rf * 16 + lg * 4 + r;  // C/D: row=(lane>>4)*4+reg
                float vv = sdinv[lr] * acc[rf][nf][r] + bb;
                if (RELU) vv = fmaxf(vv, 0.f);
                size_t o = ((size_t)b * NPTS + row0 + lr) * BN + gc;
                if (F32OUT) ((float*)outp)[o] = vv;
                else        ((unsigned short*)outp)[o] = f2b(vv);
            }
        }
    }
}

// ---------------- kernel: dense small GEMM  Y = dinv_row * (H @ W) ----------------
template<int BN, int KTOT>
__global__ __launch_bounds__(256) void k_hw(const unsigned short* __restrict__ H,
                                            const unsigned short* __restrict__ Wb,
                                            const float* __restrict__ dinv,
                                            unsigned short* __restrict__ Yo) {
    constexpr int BK = 64, BM = 128, LDT = BK + 8;
    const int row0 = blockIdx.x * BM;  // flat row (b*N+i)
    const int tid = threadIdx.x;
    const int lane = tid & 63, wv = tid >> 6;
    const int l15 = lane & 15, lg = lane >> 4;

    __shared__ alignas(16) unsigned short At[BM][LDT];
    __shared__ alignas(16) unsigned short Wt[BN][LDT];

    f32x4 acc[2][BN / 16];
    #pragma unroll
    for (int rf = 0; rf < 2; ++rf)
        #pragma unroll
        for (int nf = 0; nf < BN / 16; ++nf)
            acc[rf][nf] = (f32x4){0.f, 0.f, 0.f, 0.f};

    for (int kt = 0; kt < KTOT / BK; ++kt) {
        const uint32_t* asrc = (const uint32_t*)(H + (size_t)row0 * KTOT + kt * BK);
        #pragma unroll 4
        for (int idx = tid; idx < BM * BK / 2; idx += 256) {
            int r = idx >> 5, kp = idx & 31;
            *(uint32_t*)&At[r][2 * kp] = asrc[(size_t)r * (KTOT / 2) + kp];
        }
        const uint32_t* wsrc = (const uint32_t*)(Wb + (size_t)kt * BK * BN);
        #pragma unroll 4
        for (int idx = tid; idx < BK * BN / 2; idx += 256) {
            int j = idx / (BN / 2), cp = idx % (BN / 2);
            uint32_t val = wsrc[(size_t)j * (BN / 2) + cp];
            Wt[2 * cp][j]     = (unsigned short)(val & 0xffffu);
            Wt[2 * cp + 1][j] = (unsigned short)(val >> 16);
        }
        __syncthreads();
        #pragma unroll
        for (int kk = 0; kk < BK; kk += 32) {
            bf16x8 afr0 = *(const bf16x8*)&At[wv * 32 + l15][kk + lg * 8];
            bf16x8 afr1 = *(const bf16x8*)&At[wv * 32 + 16 + l15][kk + lg * 8];
            #pragma unroll
            for (int nf = 0; nf < BN / 16; ++nf) {
                bf16x8 bfr = *(const bf16x8*)&Wt[nf * 16 + l15][kk + lg * 8];
                acc[0][nf] = __builtin_amdgcn_mfma_f32_16x16x32_bf16(afr0, bfr, acc[0][nf], 0, 0, 0);
                acc[1][nf] = __builtin_amdgcn_mfma_f32_16x16x32_bf16(afr1, bfr, acc[1][nf], 0, 0, 0);
            }
        }
        __syncthreads();
    }

    #pragma unroll
    for (int rf = 0; rf < 2; ++rf) {
        #pragma unroll
        for (int nf = 0; nf < BN / 16; ++nf) {
            const int gc = nf * 16 + l15;
            #pragma unroll
            for (int r = 0; r < 4; ++r) {
                const int lr = wv * 32 + rf * 16 + lg * 4 + r;
                const int grow = row0 + lr;
                float vv = dinv[grow] * acc[rf][nf][r];
                Yo[(size_t)grow * BN + gc] = f2b(vv);
            }
        }
    }
}

extern "C" void kernel_launch(void* const* d_in, const int* in_sizes, int n_in,
                              void* d_out, int out_size, void* d_ws, size_t ws_size,
                              hipStream_t stream) {
    const float* pts = (const float*)d_in[0];
    const float* W1  = (const float*)d_in[1];
    const float* b1  = (const float*)d_in[2];
    const float* W2  = (const float*)d_in[3];
    const float* b2  = (const float*)d_in[4];
    const float* W3  = (const float*)d_in[5];
    const float* b3  = (const float*)d_in[6];

    char* ws = (char*)d_ws;
    float*          dinv = (float*)(ws + OFF_DINV);
    uint32_t*       mask = (uint32_t*)(ws + OFF_MASK);
    unsigned short* Y    = (unsigned short*)(ws + OFF_Y);
    unsigned short* H    = (unsigned short*)(ws + OFF_H);
    unsigned short* Wb   = (unsigned short*)(ws + OFF_WB);
    float* out = (float*)d_out;

    // W2/W3 -> bf16
    k_cvtW<<<dim3(128), dim3(256), 0, stream>>>(W2, W3, Wb);
    // adjacency bitmask + dinv
    k_mask<<<dim3(NPTS / 256, BATCH), dim3(256), 0, stream>>>(pts, dinv, mask);
    // layer 1: H1 = relu(dinv*(A @ (dinv*p)) @ W1 + b1)   [N x 64]
    k_layer1<<<dim3(NPTS / 256, BATCH), dim3(256), 0, stream>>>(pts, W1, b1, dinv, mask, H);
    // Y2 = dinv * (H1 @ W2)   [N x 128]
    k_hw<128, 64><<<dim3(BATCH * NPTS / 128), dim3(256), 0, stream>>>(H, Wb, dinv, Y);
    // layer 2: H2 = relu(dinv*(A@Y2) + b2)   [N x 128]
    k_gcn<128, true, false><<<dim3(NPTS / 128, BATCH), dim3(256), 0, stream>>>(mask, dinv, Y, b2, H);
    // Y3 = dinv * (H2 @ W3)   [N x 256]
    k_hw<256, 128><<<dim3(BATCH * NPTS / 128), dim3(256), 0, stream>>>(H, Wb + 64 * 128, dinv, Y);
    // layer 3: out = dinv*(A@Y3) + b3   [N x 256] fp32
    k_gcn<256, false, true><<<dim3(NPTS / 128, BATCH), dim3(256), 0, stream>>>(mask, dinv, Y, b3, out);
}

// Round 2
// 326.051 us; speedup vs baseline: 1.9140x; 1.9140x over previous
//
#include <hip/hip_runtime.h>
#include <hip/hip_bf16.h>
#include <cstdint>
#include <cstddef>

#define BATCH 32
#define NPTS  2048
#define NFLAT (BATCH * NPTS)   // 65536

typedef __attribute__((ext_vector_type(8))) short bf16x8;   // 8 bf16 (4 VGPRs)
typedef __attribute__((ext_vector_type(4))) float f32x4;    // C/D frag

__device__ inline unsigned short f2b(float v) {
    __hip_bfloat16 h = __float2bfloat16(v);
    return __builtin_bit_cast(unsigned short, h);
}

__device__ inline void gl_lds16(const void* g, void* l) {
    __builtin_amdgcn_global_load_lds(
        (const __attribute__((address_space(1))) unsigned int*)g,
        (__attribute__((address_space(3))) unsigned int*)l, 16, 0, 0);
}

// ---------------- ws layout (bytes) ----------------
// dinv : f32  [65536]        @ 0          (256 KB)
// mask : u32  [65536*64]     @ 262144     (16 MB)
// Yt   : bf16 [256][65536]   @ 17039360   (32 MB)  transposed dinv-scaled H@W
// H    : bf16 [65536*128max] @ 50593792   (16 MB)  row-major activations
// Wb   : bf16 [8192+32768]   @ 67371008   (80 KB)
#define OFF_DINV 0
#define OFF_MASK 262144
#define OFF_YT   17039360
#define OFF_H    50593792
#define OFF_WB   67371008

// ---------------- convert W2/W3 to bf16 ----------------
__global__ __launch_bounds__(256) void k_cvtW(const float* __restrict__ W2,
                                              const float* __restrict__ W3,
                                              unsigned short* __restrict__ Wb) {
    int i = blockIdx.x * 256 + threadIdx.x;
    if (i < 64 * 128)  Wb[i] = f2b(W2[i]);
    if (i < 128 * 256) Wb[64 * 128 + i] = f2b(W3[i]);
}

// ---------------- adjacency bitmask + dinv ----------------
__global__ __launch_bounds__(256) void k_mask(const float* __restrict__ pts,
                                              float* __restrict__ dinv,
                                              uint32_t* __restrict__ mask) {
    const int b = blockIdx.y;
    const int i = blockIdx.x * 256 + threadIdx.x;
    __shared__ float px[NPTS], py[NPTS];
    const float2* P = (const float2*)(pts + (size_t)b * NPTS * 2);
    for (int j = threadIdx.x; j < NPTS; j += 256) { float2 p = P[j]; px[j] = p.x; py[j] = p.y; }
    __syncthreads();
    const float xi = px[i], yi = py[i];
    uint32_t* mrow = mask + ((size_t)b * NPTS + i) * 64;
    int cnt = 0;
    for (int w = 0; w < 64; ++w) {
        uint32_t bits = 0;
        const int j0 = w * 32;
        #pragma unroll
        for (int t = 0; t < 32; ++t) {
            float dx = xi - px[j0 + t], dy = yi - py[j0 + t];
            bits |= (dx * dx + dy * dy < 1.0f) ? (1u << t) : 0u;
        }
        cnt += __popc(bits);
        mrow[w] = bits;
    }
    dinv[b * NPTS + i] = 1.0f / sqrtf((float)(cnt + 1));  // self-bit + extra self-loop
}

// ---------------- layer 1 via (An@p)@W1 (K=2 trick) ----------------
__global__ __launch_bounds__(256) void k_layer1(const float* __restrict__ pts,
                                                const float* __restrict__ W1,
                                                const float* __restrict__ b1,
                                                const float* __restrict__ dinv,
                                                const uint32_t* __restrict__ mask,
                                                unsigned short* __restrict__ H) {
    const int b = blockIdx.y;
    const int i = blockIdx.x * 256 + threadIdx.x;
    __shared__ float u[NPTS], v[NPTS];
    const float2* P = (const float2*)(pts + (size_t)b * NPTS * 2);
    const float* dv = dinv + b * NPTS;
    for (int j = threadIdx.x; j < NPTS; j += 256) {
        float d = dv[j]; float2 p = P[j];
        u[j] = d * p.x; v[j] = d * p.y;
    }
    __syncthreads();
    const uint32_t* mrow = mask + ((size_t)b * NPTS + i) * 64;
    float sx = 0.f, sy = 0.f;
    for (int w = 0; w < 64; ++w) {
        uint32_t bits = mrow[w];
        const int j0 = w * 32;
        #pragma unroll
        for (int t = 0; t < 32; ++t) {
            if (bits & (1u << t)) { sx += u[j0 + t]; sy += v[j0 + t]; }
        }
    }
    sx += u[i]; sy += v[i];   // diag weight 2
    const float di = dv[i];
    unsigned short* h = H + ((size_t)b * NPTS + i) * 64;
    #pragma unroll
    for (int c = 0; c < 64; ++c) {
        float val = di * (sx * W1[c] + sy * W1[64 + c]) + b1[c];
        h[c] = f2b(fmaxf(val, 0.f));
    }
}

// ---------------- Yt = dinv_i * (H @ W)^T   (computed as W^T @ H^T) ----------------
// All reads contiguous: Wt transposed once in LDS (+8 pad), H b128 straight from global.
template<int CW, int KT>   // CW: W col-count (full), KT: K dim
__global__ __launch_bounds__(256, 2) void k_hwT(const unsigned short* __restrict__ H,
                                                const unsigned short* __restrict__ Wg,
                                                const float* __restrict__ dinv,
                                                unsigned short* __restrict__ Yt) {
    constexpr int BI = 256, BC = 128;
    const int i0 = blockIdx.x * BI;
    const int c0 = blockIdx.y * BC;
    const int tid = threadIdx.x, lane = tid & 63, wv = tid >> 6;
    const int l15 = lane & 15, lg = lane >> 4;

    __shared__ unsigned short Wt[BC][KT + 8];
    for (int idx = tid; idx < BC * KT; idx += 256) {
        int c = idx & (BC - 1), k = idx >> 7;
        Wt[c][k] = Wg[(size_t)k * CW + c0 + c];
    }
    __syncthreads();

    const int iw0 = i0 + wv * 64;
    bf16x8 hb[4][KT / 32];
    #pragma unroll
    for (int if_ = 0; if_ < 4; ++if_) {
        const unsigned short* hrow = H + (size_t)(iw0 + if_ * 16 + l15) * KT;
        #pragma unroll
        for (int kq = 0; kq < KT / 32; ++kq)
            hb[if_][kq] = *(const bf16x8*)(hrow + kq * 32 + lg * 8);
    }

    f32x4 acc[8][4];
    #pragma unroll
    for (int cf = 0; cf < 8; ++cf)
        #pragma unroll
        for (int if_ = 0; if_ < 4; ++if_)
            acc[cf][if_] = (f32x4){0.f, 0.f, 0.f, 0.f};

    #pragma unroll
    for (int kq = 0; kq < KT / 32; ++kq)
        #pragma unroll
        for (int cf = 0; cf < 8; ++cf) {
            bf16x8 wa = *(const bf16x8*)&Wt[cf * 16 + l15][kq * 32 + lg * 8];
            #pragma unroll
            for (int if_ = 0; if_ < 4; ++if_)
                acc[cf][if_] = __builtin_amdgcn_mfma_f32_16x16x32_bf16(wa, hb[if_][kq], acc[cf][if_], 0, 0, 0);
        }

    float dv[4];
    #pragma unroll
    for (int if_ = 0; if_ < 4; ++if_) dv[if_] = dinv[iw0 + if_ * 16 + l15];
    #pragma unroll
    for (int cf = 0; cf < 8; ++cf)
        #pragma unroll
        for (int if_ = 0; if_ < 4; ++if_) {
            const int ig = iw0 + if_ * 16 + l15;
            #pragma unroll
            for (int r = 0; r < 4; ++r) {
                const int cg = c0 + cf * 16 + lg * 4 + r;
                Yt[(size_t)cg * NFLAT + ig] = f2b(dv[if_] * acc[cf][if_][r]);
            }
        }
}

// ---------------- masked GCN GEMM: out = act(dinv_i*((mask+I) @ Y) + bias) ----------------
// A generated from bitmask via LDS LUT; Y staged via global_load_lds w/ XOR swizzle.
template<int BN, bool RELU, bool F32OUT>
__global__ __launch_bounds__(256, 2) void k_gcnM(const uint32_t* __restrict__ mask,
                                                 const float* __restrict__ dinv,
                                                 const unsigned short* __restrict__ Yt,
                                                 const float* __restrict__ bias,
                                                 void* __restrict__ outp) {
    constexpr int BM = 128;
    constexpr int NF = BN / 32;           // n-frags per wave (2x2 wave grid)
    const int lid = blockIdx.x;
    const int g = (lid & 7) * 64 + (lid >> 3);   // bijective XCD swizzle: 4 batches/XCD
    const int b = g >> 4;
    const int row0 = (g & 15) * BM;
    const int tid = threadIdx.x;
    const int lane = tid & 63, wv = tid >> 6;
    const int wm = wv >> 1, wn = wv & 1;
    const int l15 = lane & 15, lg = lane >> 4;

    __shared__ alignas(16) unsigned short Ys[BN * 64];   // swizzled [c][64]
    __shared__ uint32_t Ms[BM * 66];                     // mask rows, pad->66
    __shared__ alignas(16) unsigned short LUT[256 * 8];  // byte -> 8 bf16 {0,1}
    __shared__ float sdinv[BM];

    {
        bf16x8 e;
        #pragma unroll
        for (int i = 0; i < 8; ++i) e[i] = (short)(((tid >> i) & 1) ? 0x3F80 : 0);
        *(bf16x8*)&LUT[tid * 8] = e;
    }
    if (tid < BM) sdinv[tid] = dinv[b * NPTS + row0 + tid];
    {
        const uint32_t* msrc = mask + ((size_t)b * NPTS + row0) * 64;
        for (int idx = tid; idx < BM * 64; idx += 256) {
            int r = idx >> 6, w = idx & 63;
            Ms[r * 66 + w] = msrc[(size_t)r * 64 + w];
        }
    }

    f32x4 acc[4][NF];
    #pragma unroll
    for (int mf = 0; mf < 4; ++mf)
        #pragma unroll
        for (int nf = 0; nf < NF; ++nf)
            acc[mf][nf] = (f32x4){0.f, 0.f, 0.f, 0.f};

    const int ktd = (row0 >> 6) + wm;   // K-tile containing this wave's diagonal (uniform)
    const int cst = lane >> 3;          // staging sub-row
    const int sst = lane & 7;           // staging stored slot

    for (int kt = 0; kt < NPTS / 64; ++kt) {
        // ---- stage Yt tile, linear LDS dest + inverse-swizzled global source ----
        #pragma unroll
        for (int q = 0; q < BN / 32; ++q) {
            int j = wv * (BN / 32) + q;
            int c = j * 8 + cst;
            int slot = sst ^ (c & 7);
            const unsigned short* gsrc = Yt + (size_t)c * NFLAT + b * NPTS + kt * 64 + slot * 8;
            gl_lds16(gsrc, (char*)Ys + j * 1024);
        }
        asm volatile("s_waitcnt vmcnt(0)" ::: "memory");
        __syncthreads();

        #pragma unroll
        for (int kk = 0; kk < 64; kk += 32) {
            bf16x8 af[4];
            #pragma unroll
            for (int mf = 0; mf < 4; ++mf) {
                int r = wm * 64 + mf * 16 + l15;
                uint32_t mw = Ms[r * 66 + (kt << 1) + (kk >> 5)];
                uint32_t by = (mw >> (lg * 8)) & 0xffu;
                af[mf] = *(const bf16x8*)&LUT[by << 3];
            }
            if (kt == ktd) {   // bump diagonal 1.0 -> 2.0 (self-loop doubling)
                #pragma unroll
                for (int mf = 0; mf < 4; ++mf) {
                    int e = mf * 16 + l15 - kk - lg * 8;
                    #pragma unroll
                    for (int e2 = 0; e2 < 8; ++e2)
                        if (e2 == e) af[mf][e2] = (short)0x4000;
                }
            }
            #pragma unroll
            for (int nf = 0; nf < NF; ++nf) {
                int c = wn * (BN / 2) + nf * 16 + l15;
                int slot = ((kk >> 3) + lg) ^ (c & 7);
                bf16x8 bf = *(const bf16x8*)((const char*)Ys + c * 128 + slot * 16);
                #pragma unroll
                for (int mf = 0; mf < 4; ++mf)
                    acc[mf][nf] = __builtin_amdgcn_mfma_f32_16x16x32_bf16(af[mf], bf, acc[mf][nf], 0, 0, 0);
            }
        }
        __syncthreads();
    }

    // ---- epilogue ----
    #pragma unroll
    for (int mf = 0; mf < 4; ++mf) {
        #pragma unroll
        for (int nf = 0; nf < NF; ++nf) {
            const int gc = wn * (BN / 2) + nf * 16 + l15;
            const float bb = bias[gc];
            #pragma unroll
            for (int r = 0; r < 4; ++r) {
                const int lr = wm * 64 + mf * 16 + lg * 4 + r;
                float vv = sdinv[lr] * acc[mf][nf][r] + bb;
                if (RELU) vv = fmaxf(vv, 0.f);
                size_t o = ((size_t)(b * NPTS + row0 + lr)) * BN + gc;
                if (F32OUT) ((float*)outp)[o] = vv;
                else        ((unsigned short*)outp)[o] = f2b(vv);
            }
        }
    }
}

extern "C" void kernel_launch(void* const* d_in, const int* in_sizes, int n_in,
                              void* d_out, int out_size, void* d_ws, size_t ws_size,
                              hipStream_t stream) {
    const float* pts = (const float*)d_in[0];
    const float* W1  = (const float*)d_in[1];
    const float* b1  = (const float*)d_in[2];
    const float* W2  = (const float*)d_in[3];
    const float* b2  = (const float*)d_in[4];
    const float* W3  = (const float*)d_in[5];
    const float* b3  = (const float*)d_in[6];

    char* ws = (char*)d_ws;
    float*          dinv = (float*)(ws + OFF_DINV);
    uint32_t*       mask = (uint32_t*)(ws + OFF_MASK);
    unsigned short* Yt   = (unsigned short*)(ws + OFF_YT);
    unsigned short* H    = (unsigned short*)(ws + OFF_H);
    unsigned short* Wb   = (unsigned short*)(ws + OFF_WB);
    float* out = (float*)d_out;

    k_cvtW<<<dim3(128), dim3(256), 0, stream>>>(W2, W3, Wb);
    k_mask<<<dim3(NPTS / 256, BATCH), dim3(256), 0, stream>>>(pts, dinv, mask);
    // layer 1: H1 = relu(An @ (p@W1) + b1)   [65536 x 64] row-major
    k_layer1<<<dim3(NPTS / 256, BATCH), dim3(256), 0, stream>>>(pts, W1, b1, dinv, mask, H);
    // Yt2 = dinv * (H1 @ W2)^T   [128][65536]
    k_hwT<128, 64><<<dim3(NFLAT / 256, 1), dim3(256), 0, stream>>>(H, Wb, dinv, Yt);
    // layer 2: H2 = relu(dinv*((mask+I)@Y2) + b2)   [65536 x 128]
    k_gcnM<128, true, false><<<dim3(512), dim3(256), 0, stream>>>(mask, dinv, Yt, b2, H);
    // Yt3 = dinv * (H2 @ W3)^T   [256][65536]
    k_hwT<256, 128><<<dim3(NFLAT / 256, 2), dim3(256), 0, stream>>>(H, Wb + 64 * 128, dinv, Yt);
    // layer 3: out = dinv*((mask+I)@Y3) + b3   fp32
    k_gcnM<256, false, true><<<dim3(512), dim3(256), 0, stream>>>(mask, dinv, Yt, b3, out);
}

// Round 3
// 194.527 us; speedup vs baseline: 3.2081x; 1.6761x over previous
//
#include <hip/hip_runtime.h>
#include <hip/hip_bf16.h>
#include <cstdint>
#include <cstddef>

#define BATCH 32
#define NPTS  2048
#define NFLAT (BATCH * NPTS)   // 65536
#define MROWS 32               // rows per block in mask/layer1 (8 per wave)

typedef __attribute__((ext_vector_type(8))) short bf16x8;   // 8 bf16 (4 VGPRs)
typedef __attribute__((ext_vector_type(4))) float f32x4;    // C/D frag

__device__ inline unsigned short f2b(float v) {
    __hip_bfloat16 h = __float2bfloat16(v);
    return __builtin_bit_cast(unsigned short, h);
}

__device__ inline void gl_lds16(const void* g, void* l) {
    __builtin_amdgcn_global_load_lds(
        (const __attribute__((address_space(1))) unsigned int*)g,
        (__attribute__((address_space(3))) unsigned int*)l, 16, 0, 0);
}

// ---------------- ws layout (bytes) ----------------
#define OFF_DINV 0
#define OFF_MASK 262144
#define OFF_YT   17039360
#define OFF_H    50593792
#define OFF_WB   67371008

// ---------------- convert W2/W3 to bf16 ----------------
__global__ __launch_bounds__(256) void k_cvtW(const float* __restrict__ W2,
                                              const float* __restrict__ W3,
                                              unsigned short* __restrict__ Wb) {
    int i = blockIdx.x * 256 + threadIdx.x;
    if (i < 64 * 128)  Wb[i] = f2b(W2[i]);
    if (i < 128 * 256) Wb[64 * 128 + i] = f2b(W3[i]);
}

// ---------------- adjacency bitmask + dinv (wave-per-row) ----------------
// Lane l computes mask word l (bits for j in [32l,32l+32)). Points staged in LDS
// with +1/32 pad: idx = j + (j>>5); lane l reads 33l+t -> bank (l+t)%32, conflict-free.
__global__ __launch_bounds__(256) void k_mask(const float* __restrict__ pts,
                                              float* __restrict__ dinv,
                                              uint32_t* __restrict__ mask) {
    const int b = blockIdx.y;
    const int row0 = blockIdx.x * MROWS;
    const int tid = threadIdx.x, lane = tid & 63, wv = tid >> 6;
    __shared__ float px[2112], py[2112];
    const float2* P = (const float2*)(pts + (size_t)b * NPTS * 2);
    for (int j = tid; j < NPTS; j += 256) {
        float2 p = P[j];
        px[j + (j >> 5)] = p.x; py[j + (j >> 5)] = p.y;
    }
    __syncthreads();
    const int base = 33 * lane;
    for (int rr = 0; rr < MROWS / 4; ++rr) {
        const int i = row0 + wv * (MROWS / 4) + rr;
        const float xi = px[i + (i >> 5)], yi = py[i + (i >> 5)];
        uint32_t bits = 0;
        #pragma unroll
        for (int t = 0; t < 32; ++t) {
            float dx = xi - px[base + t], dy = yi - py[base + t];
            bits |= (dx * dx + dy * dy < 1.0f) ? (1u << t) : 0u;
        }
        mask[((size_t)b * NPTS + i) * 64 + lane] = bits;
        int cnt = __popc(bits);
        #pragma unroll
        for (int off = 32; off; off >>= 1) cnt += __shfl_xor(cnt, off);
        if (lane == 0) dinv[b * NPTS + i] = rsqrtf((float)(cnt + 1));
    }
}

// ---------------- layer 1 via (An@p)@W1, wave-per-row ----------------
// Lane l sums u,v over its own mask word's j-range; branch-free via sign-mask AND.
__global__ __launch_bounds__(256) void k_layer1(const float* __restrict__ pts,
                                                const float* __restrict__ W1,
                                                const float* __restrict__ b1,
                                                const float* __restrict__ dinv,
                                                const uint32_t* __restrict__ mask,
                                                unsigned short* __restrict__ H) {
    const int b = blockIdx.y;
    const int row0 = blockIdx.x * MROWS;
    const int tid = threadIdx.x, lane = tid & 63, wv = tid >> 6;
    __shared__ float u[2112], v[2112];
    const float* dv = dinv + (size_t)b * NPTS;
    const float2* P = (const float2*)(pts + (size_t)b * NPTS * 2);
    for (int j = tid; j < NPTS; j += 256) {
        float d = dv[j]; float2 p = P[j];
        u[j + (j >> 5)] = d * p.x; v[j + (j >> 5)] = d * p.y;
    }
    __syncthreads();
    const float w1x = W1[lane], w1y = W1[64 + lane], bb = b1[lane];
    const int base = 33 * lane;
    for (int rr = 0; rr < MROWS / 4; ++rr) {
        const int i = row0 + wv * (MROWS / 4) + rr;
        const uint32_t wreg = mask[((size_t)b * NPTS + i) * 64 + lane];
        float sx = 0.f, sy = 0.f;
        #pragma unroll
        for (int t = 0; t < 32; ++t) {
            uint32_t m = 0u - ((wreg >> t) & 1u);
            sx += __uint_as_float(__float_as_uint(u[base + t]) & m);
            sy += __uint_as_float(__float_as_uint(v[base + t]) & m);
        }
        #pragma unroll
        for (int off = 32; off; off >>= 1) {
            sx += __shfl_xor(sx, off);
            sy += __shfl_xor(sy, off);
        }
        sx += u[i + (i >> 5)]; sy += v[i + (i >> 5)];   // extra self-loop (diag weight 2)
        const float di = dv[i];
        float val = di * (sx * w1x + sy * w1y) + bb;
        H[((size_t)b * NPTS + i) * 64 + lane] = f2b(fmaxf(val, 0.f));
    }
}

// ---------------- Yt = dinv_i * (H @ W)^T   (computed as W^T @ H^T) ----------------
template<int CW, int KT>
__global__ __launch_bounds__(256, 2) void k_hwT(const unsigned short* __restrict__ H,
                                                const unsigned short* __restrict__ Wg,
                                                const float* __restrict__ dinv,
                                                unsigned short* __restrict__ Yt) {
    constexpr int BI = 256, BC = 128;
    const int i0 = blockIdx.x * BI;
    const int c0 = blockIdx.y * BC;
    const int tid = threadIdx.x, lane = tid & 63, wv = tid >> 6;
    const int l15 = lane & 15, lg = lane >> 4;

    __shared__ unsigned short Wt[BC][KT + 8];
    for (int idx = tid; idx < BC * KT; idx += 256) {
        int c = idx & (BC - 1), k = idx >> 7;
        Wt[c][k] = Wg[(size_t)k * CW + c0 + c];
    }
    __syncthreads();

    const int iw0 = i0 + wv * 64;
    bf16x8 hb[4][KT / 32];
    #pragma unroll
    for (int if_ = 0; if_ < 4; ++if_) {
        const unsigned short* hrow = H + (size_t)(iw0 + if_ * 16 + l15) * KT;
        #pragma unroll
        for (int kq = 0; kq < KT / 32; ++kq)
            hb[if_][kq] = *(const bf16x8*)(hrow + kq * 32 + lg * 8);
    }

    f32x4 acc[8][4];
    #pragma unroll
    for (int cf = 0; cf < 8; ++cf)
        #pragma unroll
        for (int if_ = 0; if_ < 4; ++if_)
            acc[cf][if_] = (f32x4){0.f, 0.f, 0.f, 0.f};

    #pragma unroll
    for (int kq = 0; kq < KT / 32; ++kq)
        #pragma unroll
        for (int cf = 0; cf < 8; ++cf) {
            bf16x8 wa = *(const bf16x8*)&Wt[cf * 16 + l15][kq * 32 + lg * 8];
            #pragma unroll
            for (int if_ = 0; if_ < 4; ++if_)
                acc[cf][if_] = __builtin_amdgcn_mfma_f32_16x16x32_bf16(wa, hb[if_][kq], acc[cf][if_], 0, 0, 0);
        }

    float dv[4];
    #pragma unroll
    for (int if_ = 0; if_ < 4; ++if_) dv[if_] = dinv[iw0 + if_ * 16 + l15];
    #pragma unroll
    for (int cf = 0; cf < 8; ++cf)
        #pragma unroll
        for (int if_ = 0; if_ < 4; ++if_) {
            const int ig = iw0 + if_ * 16 + l15;
            #pragma unroll
            for (int r = 0; r < 4; ++r) {
                const int cg = c0 + cf * 16 + lg * 4 + r;
                Yt[(size_t)cg * NFLAT + ig] = f2b(dv[if_] * acc[cf][if_][r]);
            }
        }
}

// ---------------- masked GCN GEMM: out = act(dinv_i*((mask+I) @ Y) + bias) ----------------
template<int BN, bool RELU, bool F32OUT>
__global__ __launch_bounds__(256, 2) void k_gcnM(const uint32_t* __restrict__ mask,
                                                 const float* __restrict__ dinv,
                                                 const unsigned short* __restrict__ Yt,
                                                 const float* __restrict__ bias,
                                                 void* __restrict__ outp) {
    constexpr int BM = 128;
    constexpr int NF = BN / 32;
    const int lid = blockIdx.x;
    const int g = (lid & 7) * 64 + (lid >> 3);   // bijective XCD swizzle: 4 batches/XCD
    const int b = g >> 4;
    const int row0 = (g & 15) * BM;
    const int tid = threadIdx.x;
    const int lane = tid & 63, wv = tid >> 6;
    const int wm = wv >> 1, wn = wv & 1;
    const int l15 = lane & 15, lg = lane >> 4;

    __shared__ alignas(16) unsigned short Ys[BN * 64];
    __shared__ uint32_t Ms[BM * 66];
    __shared__ alignas(16) unsigned short LUT[256 * 8];
    __shared__ float sdinv[BM];

    {
        bf16x8 e;
        #pragma unroll
        for (int i = 0; i < 8; ++i) e[i] = (short)(((tid >> i) & 1) ? 0x3F80 : 0);
        *(bf16x8*)&LUT[tid * 8] = e;
    }
    if (tid < BM) sdinv[tid] = dinv[b * NPTS + row0 + tid];
    {
        const uint32_t* msrc = mask + ((size_t)b * NPTS + row0) * 64;
        for (int idx = tid; idx < BM * 64; idx += 256) {
            int r = idx >> 6, w = idx & 63;
            Ms[r * 66 + w] = msrc[(size_t)r * 64 + w];
        }
    }

    f32x4 acc[4][NF];
    #pragma unroll
    for (int mf = 0; mf < 4; ++mf)
        #pragma unroll
        for (int nf = 0; nf < NF; ++nf)
            acc[mf][nf] = (f32x4){0.f, 0.f, 0.f, 0.f};

    const int ktd = (row0 >> 6) + wm;
    const int cst = lane >> 3;
    const int sst = lane & 7;

    for (int kt = 0; kt < NPTS / 64; ++kt) {
        #pragma unroll
        for (int q = 0; q < BN / 32; ++q) {
            int j = wv * (BN / 32) + q;
            int c = j * 8 + cst;
            int slot = sst ^ (c & 7);
            const unsigned short* gsrc = Yt + (size_t)c * NFLAT + b * NPTS + kt * 64 + slot * 8;
            gl_lds16(gsrc, (char*)Ys + j * 1024);
        }
        asm volatile("s_waitcnt vmcnt(0)" ::: "memory");
        __syncthreads();

        #pragma unroll
        for (int kk = 0; kk < 64; kk += 32) {
            bf16x8 af[4];
            #pragma unroll
            for (int mf = 0; mf < 4; ++mf) {
                int r = wm * 64 + mf * 16 + l15;
                uint32_t mw = Ms[r * 66 + (kt << 1) + (kk >> 5)];
                uint32_t by = (mw >> (lg * 8)) & 0xffu;
                af[mf] = *(const bf16x8*)&LUT[by << 3];
            }
            if (kt == ktd) {
                #pragma unroll
                for (int mf = 0; mf < 4; ++mf) {
                    int e = mf * 16 + l15 - kk - lg * 8;
                    #pragma unroll
                    for (int e2 = 0; e2 < 8; ++e2)
                        if (e2 == e) af[mf][e2] = (short)0x4000;
                }
            }
            #pragma unroll
            for (int nf = 0; nf < NF; ++nf) {
                int c = wn * (BN / 2) + nf * 16 + l15;
                int slot = ((kk >> 3) + lg) ^ (c & 7);
                bf16x8 bf = *(const bf16x8*)((const char*)Ys + c * 128 + slot * 16);
                #pragma unroll
                for (int mf = 0; mf < 4; ++mf)
                    acc[mf][nf] = __builtin_amdgcn_mfma_f32_16x16x32_bf16(af[mf], bf, acc[mf][nf], 0, 0, 0);
            }
        }
        __syncthreads();
    }

    #pragma unroll
    for (int mf = 0; mf < 4; ++mf) {
        #pragma unroll
        for (int nf = 0; nf < NF; ++nf) {
            const int gc = wn * (BN / 2) + nf * 16 + l15;
            const float bb = bias[gc];
            #pragma unroll
            for (int r = 0; r < 4; ++r) {
                const int lr = wm * 64 + mf * 16 + lg * 4 + r;
                float vv = sdinv[lr] * acc[mf][nf][r] + bb;
                if (RELU) vv = fmaxf(vv, 0.f);
                size_t o = ((size_t)(b * NPTS + row0 + lr)) * BN + gc;
                if (F32OUT) ((float*)outp)[o] = vv;
                else        ((unsigned short*)outp)[o] = f2b(vv);
            }
        }
    }
}

extern "C" void kernel_launch(void* const* d_in, const int* in_sizes, int n_in,
                              void* d_out, int out_size, void* d_ws, size_t ws_size,
                              hipStream_t stream) {
    const float* pts = (const float*)d_in[0];
    const float* W1  = (const float*)d_in[1];
    const float* b1  = (const float*)d_in[2];
    const float* W2  = (const float*)d_in[3];
    const float* b2  = (const float*)d_in[4];
    const float* W3  = (const float*)d_in[5];
    const float* b3  = (const float*)d_in[6];

    char* ws = (char*)d_ws;
    float*          dinv = (float*)(ws + OFF_DINV);
    uint32_t*       mask = (uint32_t*)(ws + OFF_MASK);
    unsigned short* Yt   = (unsigned short*)(ws + OFF_YT);
    unsigned short* H    = (unsigned short*)(ws + OFF_H);
    unsigned short* Wb   = (unsigned short*)(ws + OFF_WB);
    float* out = (float*)d_out;

    k_cvtW<<<dim3(128), dim3(256), 0, stream>>>(W2, W3, Wb);
    k_mask<<<dim3(NPTS / MROWS, BATCH), dim3(256), 0, stream>>>(pts, dinv, mask);
    k_layer1<<<dim3(NPTS / MROWS, BATCH), dim3(256), 0, stream>>>(pts, W1, b1, dinv, mask, H);
    k_hwT<128, 64><<<dim3(NFLAT / 256, 1), dim3(256), 0, stream>>>(H, Wb, dinv, Yt);
    k_gcnM<128, true, false><<<dim3(512), dim3(256), 0, stream>>>(mask, dinv, Yt, b2, H);
    k_hwT<256, 128><<<dim3(NFLAT / 256, 2), dim3(256), 0, stream>>>(H, Wb + 64 * 128, dinv, Yt);
    k_gcnM<256, false, true><<<dim3(512), dim3(256), 0, stream>>>(mask, dinv, Yt, b3, out);
}